// Round 9
// baseline (227.227 us; speedup 1.0000x reference)
//
#include <hip/hip_runtime.h>
#include <math.h>

#define TPB 1024
#define EPT 4       // elements per thread (one float4 each of x and g)
#define NW  16      // waves per block
#define NN  4096    // row length (fixed by problem)
#define KSEL 410    // K = round(4096 * 0.1)
#define CAP 1024    // candidate list capacity (expected max bin ~95)

typedef float floatx4 __attribute__((ext_vector_type(4)));   // native vector for nontemporal store

// Monotonic float->uint key: larger float => larger unsigned key.
__device__ __forceinline__ unsigned sortkey(float f) {
    unsigned u = __float_as_uint(f);
    unsigned m = (unsigned)(((int)u) >> 31);     // 0x00000000 or 0xFFFFFFFF
    return u ^ (m | 0x80000000u);
}

template <bool USE_WS>
__global__ __launch_bounds__(TPB)
void skw_main(const float* __restrict__ x, const float* __restrict__ g,
              float* __restrict__ out, float* __restrict__ rowH,
              float* __restrict__ entAcc, float invB)
{
    const int row  = blockIdx.x;
    const int t    = threadIdx.x;
    const int w    = t >> 6;          // wave id 0..15
    const int lane = t & 63;
    const size_t rbase = (size_t)row * NN;

    unsigned key[EPT];

    __shared__ unsigned hist0[256][9];   // bin histogram: 8 slots + 1 pad (stride 9)
    __shared__ unsigned wtot[4];         // bin-scan wave chunk totals (waves 0..3)
    __shared__ unsigned wt16[NW];        // tie-scan wave totals
    __shared__ float    fred[2 * NW];
    __shared__ unsigned sh_digit, sh_above, sh_cnt, sh_thr, sh_take;

    unsigned* list = &hist0[0][0];       // aliases hist0; only written after B4 (hist0 dead)

    const float4* xp = reinterpret_cast<const float4*>(x + rbase);
    const float4* gp = reinterpret_cast<const float4*>(g + rbase);
    floatx4*      op = reinterpret_cast<floatx4*>(out + rbase);

    // ---- single load pair per thread: one HBM round-trip per wave, TLP does the rest ----
    float4 xx = xp[t];
    float4 gg = gp[t];

    // ---- entropy partials; exact s = x/10 + g (Markstein); value bins ----
    float xa[4] = {xx.x, xx.y, xx.z, xx.w};
    float ga[4] = {gg.x, gg.y, gg.z, gg.w};
    float sZ = 0.f, sZL = 0.f;
    unsigned pk = 0;
#pragma unroll
    for (int jj = 0; jj < 4; ++jj) {
        float xs = xa[jj];
        float l = xs * 0.1f;                  // y0 = RN(x * RN(0.1))
        float e = __expf(l);
        sZ  += e;
        sZL = __builtin_fmaf(e, l, sZL);
        // correctly-rounded x/10: q = y0 + (x - 10*y0)*0.1  (x/10 never at f32 midpoint)
        float q10 = __builtin_fmaf(__builtin_fmaf(-10.0f, l, xs), 0.1f, l);
        float s = q10 + ga[jj];
        key[jj] = sortkey(s);
        int b = (int)__builtin_fmaf(s, 16.0f, 64.0f);   // (s+4)*16, monotone in s
        b = min(max(b, 0), 255);
        pk |= (unsigned)b << (8 * jj);
    }

    // ---- entropy reduce (m = 0 is safe: |x*0.1| < ~0.6) ----
#pragma unroll
    for (int sft = 32; sft >= 1; sft >>= 1) { sZ += __shfl_xor(sZ, sft); sZL += __shfl_xor(sZL, sft); }
    if (lane == 0) { fred[w] = sZ; fred[NW + w] = sZL; }

    // zero bin histogram (+ counter)
    unsigned* h0 = &hist0[0][0];
    for (int i = t; i < 256 * 9; i += TPB) h0[i] = 0;
    if (t == 0) sh_cnt = 0;
    __syncthreads();                                   // B1

    if (t == 0) {
        float Z = 0.f, L = 0.f;
#pragma unroll
        for (int c = 0; c < NW; ++c) { Z += fred[c]; L += fred[NW + c]; }
        float H = __logf(Z) - L / Z;                   // H = lnZ - E[l]
        if (USE_WS) rowH[row] = H;
        else atomicAdd(entAcc, H * invB);
    }

    // ---- value-bin histogram (near-uniform bins; 8-way slot split kills serialization) ----
#pragma unroll
    for (int jj = 0; jj < 4; ++jj)
        atomicAdd(&hist0[(pk >> (8 * jj)) & 255u][lane & 7], 1u);
    __syncthreads();                                   // B2

    // merge slots + inclusive suffix scan to find crossing bin B* (threads 0..255 = waves 0..3)
    if (t < 256) {
        unsigned v = 0;
#pragma unroll
        for (int k = 0; k < 8; ++k) v += hist0[t][k];
#pragma unroll
        for (int sft = 1; sft < 64; sft <<= 1) {
            unsigned tmp = __shfl(v, lane + sft);
            v += (lane + sft < 64) ? tmp : 0u;
        }
        if (lane == 0) wtot[w] = v;
        unsigned vnext = __shfl(v, lane + 1);
        __syncthreads();                               // B3 (taken by t<256)
        unsigned hi = 0;
#pragma unroll
        for (int c = 0; c < 4; ++c) hi += (c > w) ? wtot[c] : 0u;
        unsigned cum     = v + hi;                          // # keys with bin >= t
        unsigned cumNext = ((lane < 63) ? vnext : 0u) + hi; // # keys with bin >  t
        if (cum >= KSEL && cumNext < KSEL) { sh_digit = (unsigned)t; sh_above = cumNext; }
    } else {
        __syncthreads();                               // B3 (taken by t>=256)
    }
    __syncthreads();                                   // B4
    const unsigned Bstar = sh_digit;
    const unsigned Kr = KSEL - sh_above;  // 1-based rank of threshold within bin B* (from largest)

    // ---- append candidates (bin == B*) to LDS list; exact rank among ~25-95 keys ----
#pragma unroll
    for (int jj = 0; jj < 4; ++jj) {
        if (((pk >> (8 * jj)) & 255u) == Bstar) {
            unsigned p = atomicAdd(&sh_cnt, 1u);
            if (p < CAP) list[p] = key[jj];
        }
    }
    __syncthreads();                                   // B5

    const unsigned M = sh_cnt;                         // = count of keys in bin B*
    for (unsigned i = t; i < M; i += TPB) {
        unsigned ki = list[i];
        unsigned gt = 0, eqc = 0;
        for (unsigned j2 = 0; j2 < M; ++j2) {
            unsigned kj = list[j2];                    // broadcast read
            gt  += (kj > ki) ? 1u : 0u;
            eqc += (kj == ki) ? 1u : 0u;
        }
        if (gt < Kr && Kr <= gt + eqc) { sh_thr = ki; sh_take = Kr - gt; }  // unique value
    }
    __syncthreads();                                   // B6
    const unsigned thr    = sh_thr;    // exact K-th largest key overall
    const unsigned KrTake = sh_take;   // # equal keys to accept (lowest column index first)

    // ===== lowest-index-first ties: exclusive prefix of equal counts over thread order =====
    // column c = 4*t + jj, monotone in (t, jj) -> plain 1024-thread scan.
    unsigned eq = 0;
#pragma unroll
    for (int jj = 0; jj < 4; ++jj) eq += (key[jj] == thr) ? 1u : 0u;
    unsigned sv = eq;
#pragma unroll
    for (int sft = 1; sft < 64; sft <<= 1) {           // inclusive prefix scan within wave
        unsigned tmp = __shfl(sv, lane - sft);
        sv += (lane >= sft) ? tmp : 0u;
    }
    if (lane == 63) wt16[w] = sv;                      // wave total
    __syncthreads();                                   // B7
    unsigned offset = 0;
#pragma unroll
    for (int c = 0; c < NW; ++c) offset += (c < w) ? wt16[c] : 0u;
    unsigned pos = offset + sv - eq;                   // equals in columns before mine

    // ---- write out = x * mask (coalesced full-line nontemporal store) ----
    float vals[4];
#pragma unroll
    for (int jj = 0; jj < 4; ++jj) {
        bool sel;
        if (key[jj] > thr)       sel = true;
        else if (key[jj] == thr) { sel = (pos < KrTake); ++pos; }
        else                     sel = false;
        vals[jj] = sel ? xa[jj] : 0.0f;
    }
    floatx4 o4;
    o4.x = vals[0]; o4.y = vals[1]; o4.z = vals[2]; o4.w = vals[3];
    __builtin_nontemporal_store(o4, &op[t]);
}

__global__ void skw_zero(float* p) { *p = 0.0f; }

// Deterministic fixed-order mean of rowH -> out scalar.
__global__ void skw_reduce(const float* __restrict__ rowH, float* __restrict__ outp, int B)
{
    __shared__ float red[256];
    int t = threadIdx.x;
    float s = 0.f;
    for (int i = t; i < B; i += 256) s += rowH[i];
    red[t] = s; __syncthreads();
    for (int st = 128; st > 0; st >>= 1) { if (t < st) red[t] += red[t + st]; __syncthreads(); }
    if (t == 0) *outp = red[0] / (float)B;
}

extern "C" void kernel_launch(void* const* d_in, const int* in_sizes, int n_in,
                              void* d_out, int out_size, void* d_ws, size_t ws_size,
                              hipStream_t stream)
{
    const float* x = (const float*)d_in[0];
    const float* g = (const float*)d_in[1];
    float* out = (float*)d_out;
    const int BN = in_sizes[0];
    const int B  = BN / NN;
    float* entp = out + (size_t)BN;

    if (ws_size >= (size_t)B * sizeof(float)) {
        float* rowH = (float*)d_ws;
        skw_main<true><<<B, TPB, 0, stream>>>(x, g, out, rowH, nullptr, 0.f);
        skw_reduce<<<1, 256, 0, stream>>>(rowH, entp, B);
    } else {
        skw_zero<<<1, 1, 0, stream>>>(entp);
        skw_main<false><<<B, TPB, 0, stream>>>(x, g, out, nullptr, entp, 1.0f / (float)B);
    }
}